// Round 2
// baseline (11416.667 us; speedup 1.0000x reference)
//
#include <hip/hip_runtime.h>
#include <hip/hip_bf16.h>
#include <string.h>

// Problem constants
#define T_STEPS 512
#define BATCH   128
#define DIM     256
#define HID     256
#define NLAYERS 4

typedef unsigned int  uint4v  __attribute__((ext_vector_type(4)));
typedef unsigned int  uint2v  __attribute__((ext_vector_type(2)));
typedef short         short8  __attribute__((ext_vector_type(8)));
typedef float         float4v __attribute__((ext_vector_type(4)));

// ws layout (TOTAL 258KB, safely under the proven 512KB):
//   [0, 256KB)        : h exchange ring, 2 slots x (8 clusters x 16 rows x 128
//                       pairs x 8B). pair = [bf16x2 packed h | 32-bit tag].
//                       2 slots are safe: any pub(r+2) store is transitively
//                       ordered after ALL wgs' accepted (tag-verified) reads
//                       of data(r); a violation would show as a tag mismatch
//                       (fail loud), never silent corruption.
//   [256KB, 256KB+2KB): advisory flags, 8 clusters x 16 wgs x 4 waves x 4B.
//                       Monotonic round counters; purely a spin HINT — data
//                       correctness rests on the in-pair tags alone.
#define SLOT_BYTES  (128 * 1024)
#define NSLOTS      2
#define HBUF_BYTES  (NSLOTS * SLOT_BYTES)
#define FLAGS_OFF   HBUF_BYTES
#define FLAG_BYTES  (8 * 16 * 4 * 4)

__device__ __forceinline__ short8 as_s8(uint4v u) {
  union { uint4v u; short8 s; } x; x.u = u; return x.s;
}
__device__ __forceinline__ float sigf(float x) {
  return 1.0f / (1.0f + __expf(-x));
}
__device__ __forceinline__ float tanh_fast(float x) {
  x = fminf(fmaxf(x, -15.0f), 15.0f);
  float e = __expf(2.0f * x);
  return (e - 1.0f) / (e + 1.0f);
}
// round-to-nearest-even f32 -> bf16 (inputs always finite here)
__device__ __forceinline__ unsigned short f2bf(float a) {
  unsigned ua = __builtin_bit_cast(unsigned, a);
  return (unsigned short)((ua + 0x7FFFu + ((ua >> 16) & 1u)) >> 16);
}
__device__ __forceinline__ unsigned pack_bf16x2(float a, float b) {
  return (unsigned)f2bf(a) | ((unsigned)f2bf(b) << 16);
}
__device__ __forceinline__ uint4v extract_frag(uint4v a, uint4v b) {
  uint4v f; f.x = a.x; f.y = a.z; f.z = b.x; f.w = b.z; return f;
}
__device__ __forceinline__ unsigned tagbad(uint4v a, uint4v b, unsigned tag) {
  return (a.y ^ tag) | (a.w ^ tag) | (b.y ^ tag) | (b.w ^ tag);
}

// 16 device-scope (sc0 sc1) 16B loads covering this lane's 8 A-fragments
// worth of [data|tag] pairs; single waitcnt. vaddr form (per-lane 64b addr).
#define GLD16(A0,B0,A1,B1,A2,B2,A3,B3,A4,B4,A5,B5,A6,B6,A7,B7, ADDR)       \
  asm volatile(                                                             \
      "global_load_dwordx4 %0, %16, off offset:0 sc0 sc1\n\t"               \
      "global_load_dwordx4 %1, %16, off offset:16 sc0 sc1\n\t"              \
      "global_load_dwordx4 %2, %16, off offset:128 sc0 sc1\n\t"             \
      "global_load_dwordx4 %3, %16, off offset:144 sc0 sc1\n\t"             \
      "global_load_dwordx4 %4, %16, off offset:256 sc0 sc1\n\t"             \
      "global_load_dwordx4 %5, %16, off offset:272 sc0 sc1\n\t"             \
      "global_load_dwordx4 %6, %16, off offset:384 sc0 sc1\n\t"             \
      "global_load_dwordx4 %7, %16, off offset:400 sc0 sc1\n\t"             \
      "global_load_dwordx4 %8, %16, off offset:512 sc0 sc1\n\t"             \
      "global_load_dwordx4 %9, %16, off offset:528 sc0 sc1\n\t"             \
      "global_load_dwordx4 %10, %16, off offset:640 sc0 sc1\n\t"            \
      "global_load_dwordx4 %11, %16, off offset:656 sc0 sc1\n\t"            \
      "global_load_dwordx4 %12, %16, off offset:768 sc0 sc1\n\t"            \
      "global_load_dwordx4 %13, %16, off offset:784 sc0 sc1\n\t"            \
      "global_load_dwordx4 %14, %16, off offset:896 sc0 sc1\n\t"            \
      "global_load_dwordx4 %15, %16, off offset:912 sc0 sc1\n\t"            \
      "s_waitcnt vmcnt(0)"                                                  \
      : "=&v"(A0), "=&v"(B0), "=&v"(A1), "=&v"(B1),                         \
        "=&v"(A2), "=&v"(B2), "=&v"(A3), "=&v"(B3),                         \
        "=&v"(A4), "=&v"(B4), "=&v"(A5), "=&v"(B5),                         \
        "=&v"(A6), "=&v"(B6), "=&v"(A7), "=&v"(B7)                          \
      : "v"(ADDR)                                                           \
      : "memory")

// Poll until every consumed pair carries tag==TAG, then unpack 8 A-frags.
// Stale reads only show OLD tags (monotonic) — never false-positive.
#define POLL8T(F0,F1,F2,F3,F4,F5,F6,F7, ADDR, TAG)                          \
  {                                                                         \
    uint4v _a0,_b0,_a1,_b1,_a2,_b2,_a3,_b3,_a4,_b4,_a5,_b5,_a6,_b6,_a7,_b7; \
    for (int _it = 0;; ++_it) {                                             \
      GLD16(_a0,_b0,_a1,_b1,_a2,_b2,_a3,_b3,_a4,_b4,_a5,_b5,_a6,_b6,_a7,_b7,\
            ADDR);                                                          \
      unsigned _bad = tagbad(_a0,_b0,TAG) | tagbad(_a1,_b1,TAG) |           \
                      tagbad(_a2,_b2,TAG) | tagbad(_a3,_b3,TAG) |           \
                      tagbad(_a4,_b4,TAG) | tagbad(_a5,_b5,TAG) |           \
                      tagbad(_a6,_b6,TAG) | tagbad(_a7,_b7,TAG);            \
      if (__all((int)(_bad == 0u)) || _it > (1 << 16)) break;               \
      if (_it >= 16) __builtin_amdgcn_s_sleep(1);                           \
    }                                                                       \
    F0 = extract_frag(_a0,_b0); F1 = extract_frag(_a1,_b1);                 \
    F2 = extract_frag(_a2,_b2); F3 = extract_frag(_a3,_b3);                 \
    F4 = extract_frag(_a4,_b4); F5 = extract_frag(_a5,_b5);                 \
    F6 = extract_frag(_a6,_b6); F7 = extract_frag(_a7,_b7);                 \
  }

// Advisory flag spin: 64 lanes each watch one publisher-wave flag dword.
// Condition is >= (publishers may legitimately run ahead). Cheap: 256B per
// wave per iteration vs 16KB for the verified poll.
#define SPINF(FAP, TAG)                                                     \
  {                                                                         \
    for (int _it = 0;; ++_it) {                                             \
      unsigned _f;                                                          \
      asm volatile("global_load_dword %0, %1, off sc0 sc1\n\t"              \
                   "s_waitcnt vmcnt(0)"                                     \
                   : "=v"(_f) : "v"(FAP) : "memory");                       \
      if (__all((int)(_f >= (unsigned)(TAG))) || _it > (1 << 17)) break;    \
      if (_it >= 24) __builtin_amdgcn_s_sleep(1);                           \
    }                                                                       \
  }

#define PUBLISH(ADDR, PACKED, TAG)                                          \
  {                                                                         \
    uint2v _pv; _pv.x = (PACKED); _pv.y = (TAG);                            \
    asm volatile("global_store_dwordx2 %0, %1, off sc0 sc1"                 \
                 :: "v"(ADDR), "v"(_pv) : "memory");                        \
  }

#define FLAGST(ADDR, VAL)                                                   \
  asm volatile("global_store_dword %0, %1, off sc0 sc1"                     \
               :: "v"(ADDR), "v"(VAL) : "memory")

#define MFMA_K8(ACC, BARR, H0,H1,H2,H3,H4,H5,H6,H7)                                  \
  ACC = __builtin_amdgcn_mfma_f32_16x16x32_bf16(as_s8(H0), BARR[0], ACC, 0, 0, 0);   \
  ACC = __builtin_amdgcn_mfma_f32_16x16x32_bf16(as_s8(H1), BARR[1], ACC, 0, 0, 0);   \
  ACC = __builtin_amdgcn_mfma_f32_16x16x32_bf16(as_s8(H2), BARR[2], ACC, 0, 0, 0);   \
  ACC = __builtin_amdgcn_mfma_f32_16x16x32_bf16(as_s8(H3), BARR[3], ACC, 0, 0, 0);   \
  ACC = __builtin_amdgcn_mfma_f32_16x16x32_bf16(as_s8(H4), BARR[4], ACC, 0, 0, 0);   \
  ACC = __builtin_amdgcn_mfma_f32_16x16x32_bf16(as_s8(H5), BARR[5], ACC, 0, 0, 0);   \
  ACC = __builtin_amdgcn_mfma_f32_16x16x32_bf16(as_s8(H6), BARR[6], ACC, 0, 0, 0);   \
  ACC = __builtin_amdgcn_mfma_f32_16x16x32_bf16(as_s8(H7), BARR[7], ACC, 0, 0, 0);

// ---------------------------------------------------------------------------
// Main recurrent kernel. 8 clusters (batch slices of 16) x 16 wgs (each owns
// 16 hidden columns) x 256 threads (4 waves). ALL tensors are FLOAT32; bf16
// exists only as MFMA operands. Weight B-frags persist in VGPRs.
// R9: scope experiment reverted (sc0-only is NOT cross-CU visible on gfx950).
// Added advisory flag pre-spin: publishers fire one extra monotonic flag
// dword per wave (no ack); the consumer wave spins on 64 flag dwords (256B/
// iter) instead of hammering 16KB/iter verified polls. The verified tag poll
// still runs once after flags pass — correctness is unchanged from R0.
// Ring shrunk to 2 slots (induction: pub(r+2) ordered after all accepted
// reads of data(r); violations fail loud via tag mismatch).
// ---------------------------------------------------------------------------
__launch_bounds__(256, 1)
__global__ void rnn_main(const float* __restrict__ x,
                         const int* __restrict__ lengths,
                         const float* __restrict__ Wr,
                         const float* __restrict__ Wz,
                         const float* __restrict__ Wl,
                         const float* __restrict__ Wt,
                         const float* __restrict__ Cx,
                         const float* __restrict__ Ch,
                         const float* __restrict__ Tr,
                         const float* __restrict__ Tz,
                         const float* __restrict__ Tn,
                         unsigned char* __restrict__ hbuf,
                         float* __restrict__ out) {
  const int tid  = threadIdx.x;
  const int lane = tid & 63;
  const int v    = tid >> 6;
  const int bid  = blockIdx.x;
  const int c    = bid & 7;    // cluster (batch slice)
  const int w    = bid >> 3;   // column-chunk owner within cluster

  __shared__ float  tiles[6][16 * 20];  // col-major, col stride 20
  __shared__ uint4v hsh[8][64];         // polled A-frag broadcast (8 KB)
  __shared__ int    len_sh[16];

  // ---- load + convert persistent weight B-fragments (one-time gather) ----
  // Fragment layout: lane l holds B[k = kt*32 + (l>>4)*8 + j][col0 + (l&15)].
  // Matrix ids: 0..2 = W{r,z,l}[256:512] (h-part), 3 = Ch, 4..6 = W{r,z,l}
  // [0:256] (x-part), 7 = Cx, 8 = Wt, 9..12 = Tr_i, 13..16 = Tz_i,
  // 17..20 = Tn_i.
  short8 Wf[6][8];
  {
    const int SCHED[4][6] = {{0, 4, 9, 10, 11, 12},
                             {1, 5, 13, 14, 15, 16},
                             {2, 6, 17, 18, 19, 20},
                             {3, 7, 8, 3, 3, 3}};
    const int colg = w * 16 + (lane & 15);
#pragma unroll
    for (int s = 0; s < 6; ++s) {
      const int m = SCHED[v][s];
      const float* base;
      int ro = 0;
      if      (m == 0)  { base = Wr; ro = 256; }
      else if (m == 1)  { base = Wz; ro = 256; }
      else if (m == 2)  { base = Wl; ro = 256; }
      else if (m == 3)  { base = Ch; }
      else if (m == 4)  { base = Wr; }
      else if (m == 5)  { base = Wz; }
      else if (m == 6)  { base = Wl; }
      else if (m == 7)  { base = Cx; }
      else if (m == 8)  { base = Wt; }
      else if (m <= 12) { base = Tr + (size_t)(m - 9)  * HID * HID; }
      else if (m <= 16) { base = Tz + (size_t)(m - 13) * HID * HID; }
      else              { base = Tn + (size_t)(m - 17) * HID * HID; }
#pragma unroll
      for (int kt = 0; kt < 8; ++kt) {
        const int k0 = ro + kt * 32 + (lane >> 4) * 8;
        short8 f;
#pragma unroll
        for (int j = 0; j < 8; ++j)
          f[j] = (short)f2bf(base[(size_t)(k0 + j) * HID + colg]);
        Wf[s][kt] = f;
      }
    }
  }

  if (tid < 16) len_sh[tid] = lengths[c * 16 + tid];
  __syncthreads();

  const int row = tid >> 4;
  const int col = tid & 15;
  const int mylen = len_sh[row];
  const int ci = col * 20 + row;

  float hreg = 0.0f, hprev = 0.0f;

  // lane byte offset into an h slot for A-frag [data|tag] pair loads:
  // pairs laid out [c*16+row][128 pairs]; lane reads row (lane&15),
  // quarter (lane>>4): base = row*1024 + (lane>>4)*32, frag kt at +kt*128.
  const unsigned vh = (unsigned)((c * 16 + (lane & 15)) * 1024 + (lane >> 4) * 32);
  // per-EVEN-thread publish offset: row=tid>>4, colpair=(tid&15)>>1
  const unsigned pub_off =
      (unsigned)(((c * 16 + (tid >> 4)) * 128 + w * 8 + ((tid & 15) >> 1)) * 8);
  // advisory flags: consumer lane watches publisher (w=lane>>2, v=lane&3)
  const unsigned char* fcon = hbuf + FLAGS_OFF + (size_t)(c * 64 + lane) * 4;
  unsigned char*       fpub = hbuf + FLAGS_OFF +
                              (size_t)((c * 16 + w) * 4 + v) * 4;
  const float* xbase =
      x + ((size_t)c * 16 + (lane & 15)) * DIM + (lane >> 4) * 8;

  for (int t = 0; t < T_STEPS; ++t) {
    const int r0 = t * 5;
    // ======================= round A (cell gates) =======================
    {
      const float* xp = xbase + (size_t)t * BATCH * DIM;
      uint4v xf[8];
#pragma unroll
      for (int kt = 0; kt < 8; ++kt) {
        float4v xa = *(const float4v*)(xp + kt * 32);
        float4v xb = *(const float4v*)(xp + kt * 32 + 4);
        uint4v f;
        f.x = pack_bf16x2(xa.x, xa.y);
        f.y = pack_bf16x2(xa.z, xa.w);
        f.z = pack_bf16x2(xb.x, xb.y);
        f.w = pack_bf16x2(xb.z, xb.w);
        xf[kt] = f;
      }

      float4v a0 = {0.f, 0.f, 0.f, 0.f};
      float4v a1 = {0.f, 0.f, 0.f, 0.f};
      float4v a2 = {0.f, 0.f, 0.f, 0.f};
      // x-dependent MFMAs issue first: the MFMA pipe crunches them while
      // v0 polls / others wait at the barrier.
      if (v < 3) {
#pragma unroll
        for (int kt = 0; kt < 8; ++kt)
          a0 = __builtin_amdgcn_mfma_f32_16x16x32_bf16(as_s8(xf[kt]), Wf[1][kt], a0, 0, 0, 0);
      } else {
#pragma unroll
        for (int kt = 0; kt < 8; ++kt)
          a1 = __builtin_amdgcn_mfma_f32_16x16x32_bf16(as_s8(xf[kt]), Wf[1][kt], a1, 0, 0, 0);
#pragma unroll
        for (int kt = 0; kt < 8; ++kt)
          a2 = __builtin_amdgcn_mfma_f32_16x16x32_bf16(as_s8(xf[kt]), Wf[2][kt], a2, 0, 0, 0);
      }
      uint4v h0, h1, h2, h3, h4, h5, h6, h7;
      if (v == 0) {
        SPINF(fcon, r0);
        const unsigned char* ap =
            hbuf + (size_t)((r0 - 1) & 1) * SLOT_BYTES + vh;
        POLL8T(h0, h1, h2, h3, h4, h5, h6, h7, ap, (unsigned)r0);
        hsh[0][lane] = h0; hsh[1][lane] = h1; hsh[2][lane] = h2;
        hsh[3][lane] = h3; hsh[4][lane] = h4; hsh[5][lane] = h5;
        hsh[6][lane] = h6; hsh[7][lane] = h7;
      }
      __syncthreads();
      if (v != 0) {
        h0 = hsh[0][lane]; h1 = hsh[1][lane]; h2 = hsh[2][lane];
        h3 = hsh[3][lane]; h4 = hsh[4][lane]; h5 = hsh[5][lane];
        h6 = hsh[6][lane]; h7 = hsh[7][lane];
      }
      MFMA_K8(a0, Wf[0], h0, h1, h2, h3, h4, h5, h6, h7);
      {
        float* tp = &tiles[(v < 3) ? v : 3][(lane & 15) * 20 + (lane >> 4) * 4];
        *(float4v*)tp = a0;
        if (v == 3) {
          *(float4v*)&tiles[4][(lane & 15) * 20 + (lane >> 4) * 4] = a1;
          *(float4v*)&tiles[5][(lane & 15) * 20 + (lane >> 4) * 4] = a2;
        }
      }
      __syncthreads();
      float rp  = tiles[0][ci], zp = tiles[1][ci], lp = tiles[2][ci];
      float chv = tiles[3][ci], xcv = tiles[4][ci], xwv = tiles[5][ci];
      float r  = sigf(rp), z = sigf(zp), lg = sigf(lp);
      float n  = tanh_fast(xcv + r * chv) + lg * xwv;
      hreg = (1.0f - z) * hreg + z * n;
      // publish NOW: pair even/odd columns in-register, even threads store;
      // then each wave fires its advisory flag (unacked hint).
      {
        float hp = __shfl_xor(hreg, 1);
        if (!(tid & 1)) {
          unsigned char* pp = hbuf + (size_t)(r0 & 1) * SLOT_BYTES + pub_off;
          PUBLISH(pp, pack_bf16x2(hreg, hp), (unsigned)(r0 + 1));
        }
        if (lane == 0) { unsigned fv = (unsigned)(r0 + 1); FLAGST(fpub, fv); }
      }
    }
    // ======================= transition layers =======================
#pragma unroll
    for (int i = 0; i < NLAYERS; ++i) {
      const int ri = r0 + 1 + i;
      uint4v h0, h1, h2, h3, h4, h5, h6, h7;
      if (v == 0) {
        SPINF(fcon, ri);
        const unsigned char* ap =
            hbuf + (size_t)((ri - 1) & 1) * SLOT_BYTES + vh;
        POLL8T(h0, h1, h2, h3, h4, h5, h6, h7, ap, (unsigned)ri);
        hsh[0][lane] = h0; hsh[1][lane] = h1; hsh[2][lane] = h2;
        hsh[3][lane] = h3; hsh[4][lane] = h4; hsh[5][lane] = h5;
        hsh[6][lane] = h6; hsh[7][lane] = h7;
      }
      __syncthreads();
      if (v < 3) {
        if (v != 0) {
          h0 = hsh[0][lane]; h1 = hsh[1][lane]; h2 = hsh[2][lane];
          h3 = hsh[3][lane]; h4 = hsh[4][lane]; h5 = hsh[5][lane];
          h6 = hsh[6][lane]; h7 = hsh[7][lane];
        }
        float4v a = {0.f, 0.f, 0.f, 0.f};
        MFMA_K8(a, Wf[2 + i], h0, h1, h2, h3, h4, h5, h6, h7);
        *(float4v*)&tiles[v][(lane & 15) * 20 + (lane >> 4) * 4] = a;
      }
      __syncthreads();
      float rr = sigf(tiles[0][ci]);
      float zz = sigf(tiles[1][ci]);
      float nn = tanh_fast(rr * tiles[2][ci]);
      hreg = (1.0f - zz) * nn + zz * hreg;
      if (i == NLAYERS - 1) {
        const bool act = (t < mylen);
        float hv = act ? hreg : hprev;   // freeze h past sequence end
        float ov = act ? hreg : 0.0f;    // out = m ? hn : 0
        hreg = hv;
        hprev = hv;
        out[((size_t)t * BATCH + c * 16 + row) * HID + w * 16 + col] = ov;
      }
      {
        float hp = __shfl_xor(hreg, 1);
        if (!(tid & 1)) {
          unsigned char* pp = hbuf + (size_t)(ri & 1) * SLOT_BYTES + pub_off;
          PUBLISH(pp, pack_bf16x2(hreg, hp), (unsigned)(ri + 1));
        }
        if (lane == 0) { unsigned fv = (unsigned)(ri + 1); FLAGST(fpub, fv); }
      }
    }
  }
}

extern "C" void kernel_launch(void* const* d_in, const int* in_sizes, int n_in,
                              void* d_out, int out_size, void* d_ws, size_t ws_size,
                              hipStream_t stream) {
  (void)in_sizes; (void)n_in; (void)out_size; (void)ws_size;
  const float* x        = (const float*)d_in[0];
  const int* lengths    = (const int*)d_in[1];
  const float* Wr       = (const float*)d_in[2];
  const float* Wz       = (const float*)d_in[3];
  const float* Wl       = (const float*)d_in[4];
  const float* Wt       = (const float*)d_in[5];
  const float* Cx       = (const float*)d_in[6];
  const float* Ch       = (const float*)d_in[7];
  const float* Tr       = (const float*)d_in[8];
  const float* Tz       = (const float*)d_in[9];
  const float* Tn       = (const float*)d_in[10];

  unsigned char* hbuf = (unsigned char*)d_ws;

  // Ring init: all slots + flags zero. tag 0 == "round -1 published"; slot 1
  // data (zeros) is exactly h0; flags 0 satisfy round-0 spin (0 >= 0).
  // Must re-run every launch (ws is re-poisoned).
  hipMemsetAsync(hbuf, 0x00, HBUF_BYTES + FLAG_BYTES, stream);

  rnn_main<<<dim3(128), dim3(256), 0, stream>>>(
      x, lengths, Wr, Wz, Wl, Wt, Cx, Ch, Tr, Tz, Tn,
      hbuf, (float*)d_out);
}

// Round 3
// 10131.921 us; speedup vs baseline: 1.1268x; 1.1268x over previous
//
#include <hip/hip_runtime.h>
#include <hip/hip_bf16.h>
#include <string.h>

// Problem constants
#define T_STEPS 512
#define BATCH   128
#define DIM     256
#define HID     256
#define NLAYERS 4

typedef unsigned int  uint4v  __attribute__((ext_vector_type(4)));
typedef unsigned int  uint2v  __attribute__((ext_vector_type(2)));
typedef short         short8  __attribute__((ext_vector_type(8)));
typedef float         float4v __attribute__((ext_vector_type(4)));

// ws layout (TOTAL 512KB):
//   [0, 512KB) : h exchange ring, 4 slots x (8 clusters x 16 rows x 128 pairs
//                x 8B). pair = [bf16x2 packed h | 32-bit round tag]
//                (tag-in-data sync). R0-proven mechanism, unchanged.
#define SLOT_BYTES  (128 * 1024)
#define NSLOTS      4
#define HBUF_BYTES  (NSLOTS * SLOT_BYTES)

__device__ __forceinline__ short8 as_s8(uint4v u) {
  union { uint4v u; short8 s; } x; x.u = u; return x.s;
}
__device__ __forceinline__ float sigf(float x) {
  return 1.0f / (1.0f + __expf(-x));
}
__device__ __forceinline__ float tanh_fast(float x) {
  x = fminf(fmaxf(x, -15.0f), 15.0f);
  float e = __expf(2.0f * x);
  return (e - 1.0f) / (e + 1.0f);
}
// round-to-nearest-even f32 -> bf16 (inputs always finite here)
__device__ __forceinline__ unsigned short f2bf(float a) {
  unsigned ua = __builtin_bit_cast(unsigned, a);
  return (unsigned short)((ua + 0x7FFFu + ((ua >> 16) & 1u)) >> 16);
}
__device__ __forceinline__ unsigned pack_bf16x2(float a, float b) {
  return (unsigned)f2bf(a) | ((unsigned)f2bf(b) << 16);
}
__device__ __forceinline__ uint4v extract_frag(uint4v a, uint4v b) {
  uint4v f; f.x = a.x; f.y = a.z; f.z = b.x; f.w = b.z; return f;
}
__device__ __forceinline__ unsigned tagbad(uint4v a, uint4v b, unsigned tag) {
  return (a.y ^ tag) | (a.w ^ tag) | (b.y ^ tag) | (b.w ^ tag);
}

// 16 device-scope (sc0 sc1) 16B loads covering this lane's 8 A-fragments
// worth of [data|tag] pairs; single waitcnt. vaddr form (per-lane 64b addr).
#define GLD16(A0,B0,A1,B1,A2,B2,A3,B3,A4,B4,A5,B5,A6,B6,A7,B7, ADDR)       \
  asm volatile(                                                             \
      "global_load_dwordx4 %0, %16, off offset:0 sc0 sc1\n\t"               \
      "global_load_dwordx4 %1, %16, off offset:16 sc0 sc1\n\t"              \
      "global_load_dwordx4 %2, %16, off offset:128 sc0 sc1\n\t"             \
      "global_load_dwordx4 %3, %16, off offset:144 sc0 sc1\n\t"             \
      "global_load_dwordx4 %4, %16, off offset:256 sc0 sc1\n\t"             \
      "global_load_dwordx4 %5, %16, off offset:272 sc0 sc1\n\t"             \
      "global_load_dwordx4 %6, %16, off offset:384 sc0 sc1\n\t"             \
      "global_load_dwordx4 %7, %16, off offset:400 sc0 sc1\n\t"             \
      "global_load_dwordx4 %8, %16, off offset:512 sc0 sc1\n\t"             \
      "global_load_dwordx4 %9, %16, off offset:528 sc0 sc1\n\t"             \
      "global_load_dwordx4 %10, %16, off offset:640 sc0 sc1\n\t"            \
      "global_load_dwordx4 %11, %16, off offset:656 sc0 sc1\n\t"            \
      "global_load_dwordx4 %12, %16, off offset:768 sc0 sc1\n\t"            \
      "global_load_dwordx4 %13, %16, off offset:784 sc0 sc1\n\t"            \
      "global_load_dwordx4 %14, %16, off offset:896 sc0 sc1\n\t"            \
      "global_load_dwordx4 %15, %16, off offset:912 sc0 sc1\n\t"            \
      "s_waitcnt vmcnt(0)"                                                  \
      : "=&v"(A0), "=&v"(B0), "=&v"(A1), "=&v"(B1),                         \
        "=&v"(A2), "=&v"(B2), "=&v"(A3), "=&v"(B3),                         \
        "=&v"(A4), "=&v"(B4), "=&v"(A5), "=&v"(B5),                         \
        "=&v"(A6), "=&v"(B6), "=&v"(A7), "=&v"(B7)                          \
      : "v"(ADDR)                                                           \
      : "memory")

// Poll until every consumed pair carries tag==TAG, then unpack 8 A-frags.
// Hot spin for 16 iters, then s_sleep(1) backoff. Stale reads only show OLD
// tags (monotonic) — never false-positive.
#define POLL8T(F0,F1,F2,F3,F4,F5,F6,F7, ADDR, TAG)                          \
  {                                                                         \
    uint4v _a0,_b0,_a1,_b1,_a2,_b2,_a3,_b3,_a4,_b4,_a5,_b5,_a6,_b6,_a7,_b7; \
    for (int _it = 0;; ++_it) {                                             \
      GLD16(_a0,_b0,_a1,_b1,_a2,_b2,_a3,_b3,_a4,_b4,_a5,_b5,_a6,_b6,_a7,_b7,\
            ADDR);                                                          \
      unsigned _bad = tagbad(_a0,_b0,TAG) | tagbad(_a1,_b1,TAG) |           \
                      tagbad(_a2,_b2,TAG) | tagbad(_a3,_b3,TAG) |           \
                      tagbad(_a4,_b4,TAG) | tagbad(_a5,_b5,TAG) |           \
                      tagbad(_a6,_b6,TAG) | tagbad(_a7,_b7,TAG);            \
      if (__all((int)(_bad == 0u)) || _it > (1 << 16)) break;               \
      if (_it >= 16) __builtin_amdgcn_s_sleep(1);                           \
    }                                                                       \
    F0 = extract_frag(_a0,_b0); F1 = extract_frag(_a1,_b1);                 \
    F2 = extract_frag(_a2,_b2); F3 = extract_frag(_a3,_b3);                 \
    F4 = extract_frag(_a4,_b4); F5 = extract_frag(_a5,_b5);                 \
    F6 = extract_frag(_a6,_b6); F7 = extract_frag(_a7,_b7);                 \
  }

// R10: publish with `nt` (non-temporal). Theory: sc0 sc1 stores land DIRTY in
// the producer XCD's L2; consumer device-scope loads then pay a 3-hop
// LLC-directory->owner-L2 probe (~3-6Kcy). `nt` streams the store past L2 to
// the memory side so the line lands clean in the LLC (memory-side cache) and
// the poll load gets a 1-hop LLC hit. Pure allocation hint — same 8B atomic
// [data|tag] transaction, same device scope, correctness unchanged.
#define PUBLISH(ADDR, PACKED, TAG)                                          \
  {                                                                         \
    uint2v _pv; _pv.x = (PACKED); _pv.y = (TAG);                            \
    asm volatile("global_store_dwordx2 %0, %1, off sc0 sc1 nt"              \
                 :: "v"(ADDR), "v"(_pv) : "memory");                        \
  }

#define MFMA_K8(ACC, BARR, H0,H1,H2,H3,H4,H5,H6,H7)                                  \
  ACC = __builtin_amdgcn_mfma_f32_16x16x32_bf16(as_s8(H0), BARR[0], ACC, 0, 0, 0);   \
  ACC = __builtin_amdgcn_mfma_f32_16x16x32_bf16(as_s8(H1), BARR[1], ACC, 0, 0, 0);   \
  ACC = __builtin_amdgcn_mfma_f32_16x16x32_bf16(as_s8(H2), BARR[2], ACC, 0, 0, 0);   \
  ACC = __builtin_amdgcn_mfma_f32_16x16x32_bf16(as_s8(H3), BARR[3], ACC, 0, 0, 0);   \
  ACC = __builtin_amdgcn_mfma_f32_16x16x32_bf16(as_s8(H4), BARR[4], ACC, 0, 0, 0);   \
  ACC = __builtin_amdgcn_mfma_f32_16x16x32_bf16(as_s8(H5), BARR[5], ACC, 0, 0, 0);   \
  ACC = __builtin_amdgcn_mfma_f32_16x16x32_bf16(as_s8(H6), BARR[6], ACC, 0, 0, 0);   \
  ACC = __builtin_amdgcn_mfma_f32_16x16x32_bf16(as_s8(H7), BARR[7], ACC, 0, 0, 0);

// ---------------------------------------------------------------------------
// Main recurrent kernel. 8 clusters (batch slices of 16) x 16 wgs (each owns
// 16 hidden columns) x 256 threads (4 waves). ALL tensors are FLOAT32; bf16
// exists only as MFMA operands. Weight B-frags persist in VGPRs.
// Structure = R0-proven (4-slot tag-in-data ring, v0-only poll + LDS
// broadcast, publish-immediately-after-combine). R10 delta: `nt` on publish.
// ---------------------------------------------------------------------------
__launch_bounds__(256, 1)
__global__ void rnn_main(const float* __restrict__ x,
                         const int* __restrict__ lengths,
                         const float* __restrict__ Wr,
                         const float* __restrict__ Wz,
                         const float* __restrict__ Wl,
                         const float* __restrict__ Wt,
                         const float* __restrict__ Cx,
                         const float* __restrict__ Ch,
                         const float* __restrict__ Tr,
                         const float* __restrict__ Tz,
                         const float* __restrict__ Tn,
                         unsigned char* __restrict__ hbuf,
                         float* __restrict__ out) {
  const int tid  = threadIdx.x;
  const int lane = tid & 63;
  const int v    = tid >> 6;
  const int bid  = blockIdx.x;
  const int c    = bid & 7;    // cluster (batch slice)
  const int w    = bid >> 3;   // column-chunk owner within cluster

  __shared__ float  tiles[6][16 * 20];  // col-major, col stride 20
  __shared__ uint4v hsh[8][64];         // polled A-frag broadcast (8 KB)
  __shared__ int    len_sh[16];

  // ---- load + convert persistent weight B-fragments (one-time gather) ----
  // Fragment layout: lane l holds B[k = kt*32 + (l>>4)*8 + j][col0 + (l&15)].
  // Matrix ids: 0..2 = W{r,z,l}[256:512] (h-part), 3 = Ch, 4..6 = W{r,z,l}
  // [0:256] (x-part), 7 = Cx, 8 = Wt, 9..12 = Tr_i, 13..16 = Tz_i,
  // 17..20 = Tn_i.
  short8 Wf[6][8];
  {
    const int SCHED[4][6] = {{0, 4, 9, 10, 11, 12},
                             {1, 5, 13, 14, 15, 16},
                             {2, 6, 17, 18, 19, 20},
                             {3, 7, 8, 3, 3, 3}};
    const int colg = w * 16 + (lane & 15);
#pragma unroll
    for (int s = 0; s < 6; ++s) {
      const int m = SCHED[v][s];
      const float* base;
      int ro = 0;
      if      (m == 0)  { base = Wr; ro = 256; }
      else if (m == 1)  { base = Wz; ro = 256; }
      else if (m == 2)  { base = Wl; ro = 256; }
      else if (m == 3)  { base = Ch; }
      else if (m == 4)  { base = Wr; }
      else if (m == 5)  { base = Wz; }
      else if (m == 6)  { base = Wl; }
      else if (m == 7)  { base = Cx; }
      else if (m == 8)  { base = Wt; }
      else if (m <= 12) { base = Tr + (size_t)(m - 9)  * HID * HID; }
      else if (m <= 16) { base = Tz + (size_t)(m - 13) * HID * HID; }
      else              { base = Tn + (size_t)(m - 17) * HID * HID; }
#pragma unroll
      for (int kt = 0; kt < 8; ++kt) {
        const int k0 = ro + kt * 32 + (lane >> 4) * 8;
        short8 f;
#pragma unroll
        for (int j = 0; j < 8; ++j)
          f[j] = (short)f2bf(base[(size_t)(k0 + j) * HID + colg]);
        Wf[s][kt] = f;
      }
    }
  }

  if (tid < 16) len_sh[tid] = lengths[c * 16 + tid];
  __syncthreads();

  const int row = tid >> 4;
  const int col = tid & 15;
  const int mylen = len_sh[row];
  const int ci = col * 20 + row;

  float hreg = 0.0f, hprev = 0.0f;

  // lane byte offset into an h slot for A-frag [data|tag] pair loads:
  // pairs laid out [c*16+row][128 pairs]; lane reads row (lane&15),
  // quarter (lane>>4): base = row*1024 + (lane>>4)*32, frag kt at +kt*128.
  const unsigned vh = (unsigned)((c * 16 + (lane & 15)) * 1024 + (lane >> 4) * 32);
  // per-EVEN-thread publish offset: row=tid>>4, colpair=(tid&15)>>1
  const unsigned pub_off =
      (unsigned)(((c * 16 + (tid >> 4)) * 128 + w * 8 + ((tid & 15) >> 1)) * 8);
  const float* xbase =
      x + ((size_t)c * 16 + (lane & 15)) * DIM + (lane >> 4) * 8;

  for (int t = 0; t < T_STEPS; ++t) {
    const int r0 = t * 5;
    // ======================= round A (cell gates) =======================
    {
      const float* xp = xbase + (size_t)t * BATCH * DIM;
      uint4v xf[8];
#pragma unroll
      for (int kt = 0; kt < 8; ++kt) {
        float4v xa = *(const float4v*)(xp + kt * 32);
        float4v xb = *(const float4v*)(xp + kt * 32 + 4);
        uint4v f;
        f.x = pack_bf16x2(xa.x, xa.y);
        f.y = pack_bf16x2(xa.z, xa.w);
        f.z = pack_bf16x2(xb.x, xb.y);
        f.w = pack_bf16x2(xb.z, xb.w);
        xf[kt] = f;
      }

      float4v a0 = {0.f, 0.f, 0.f, 0.f};
      float4v a1 = {0.f, 0.f, 0.f, 0.f};
      float4v a2 = {0.f, 0.f, 0.f, 0.f};
      // x-dependent MFMAs issue first: the MFMA pipe crunches them while
      // v0 polls / others wait at the barrier.
      if (v < 3) {
#pragma unroll
        for (int kt = 0; kt < 8; ++kt)
          a0 = __builtin_amdgcn_mfma_f32_16x16x32_bf16(as_s8(xf[kt]), Wf[1][kt], a0, 0, 0, 0);
      } else {
#pragma unroll
        for (int kt = 0; kt < 8; ++kt)
          a1 = __builtin_amdgcn_mfma_f32_16x16x32_bf16(as_s8(xf[kt]), Wf[1][kt], a1, 0, 0, 0);
#pragma unroll
        for (int kt = 0; kt < 8; ++kt)
          a2 = __builtin_amdgcn_mfma_f32_16x16x32_bf16(as_s8(xf[kt]), Wf[2][kt], a2, 0, 0, 0);
      }
      uint4v h0, h1, h2, h3, h4, h5, h6, h7;
      if (v == 0) {
        const unsigned char* ap =
            hbuf + (size_t)((r0 - 1) & 3) * SLOT_BYTES + vh;
        POLL8T(h0, h1, h2, h3, h4, h5, h6, h7, ap, (unsigned)r0);
        hsh[0][lane] = h0; hsh[1][lane] = h1; hsh[2][lane] = h2;
        hsh[3][lane] = h3; hsh[4][lane] = h4; hsh[5][lane] = h5;
        hsh[6][lane] = h6; hsh[7][lane] = h7;
      }
      __syncthreads();
      if (v != 0) {
        h0 = hsh[0][lane]; h1 = hsh[1][lane]; h2 = hsh[2][lane];
        h3 = hsh[3][lane]; h4 = hsh[4][lane]; h5 = hsh[5][lane];
        h6 = hsh[6][lane]; h7 = hsh[7][lane];
      }
      MFMA_K8(a0, Wf[0], h0, h1, h2, h3, h4, h5, h6, h7);
      {
        float* tp = &tiles[(v < 3) ? v : 3][(lane & 15) * 20 + (lane >> 4) * 4];
        *(float4v*)tp = a0;
        if (v == 3) {
          *(float4v*)&tiles[4][(lane & 15) * 20 + (lane >> 4) * 4] = a1;
          *(float4v*)&tiles[5][(lane & 15) * 20 + (lane >> 4) * 4] = a2;
        }
      }
      __syncthreads();
      float rp  = tiles[0][ci], zp = tiles[1][ci], lp = tiles[2][ci];
      float chv = tiles[3][ci], xcv = tiles[4][ci], xwv = tiles[5][ci];
      float r  = sigf(rp), z = sigf(zp), lg = sigf(lp);
      float n  = tanh_fast(xcv + r * chv) + lg * xwv;
      hreg = (1.0f - z) * hreg + z * n;
      // publish NOW: pair even/odd columns in-register, even threads store.
      {
        float hp = __shfl_xor(hreg, 1);
        if (!(tid & 1)) {
          unsigned char* pp = hbuf + (size_t)(r0 & 3) * SLOT_BYTES + pub_off;
          PUBLISH(pp, pack_bf16x2(hreg, hp), (unsigned)(r0 + 1));
        }
      }
    }
    // ======================= transition layers =======================
#pragma unroll
    for (int i = 0; i < NLAYERS; ++i) {
      const int ri = r0 + 1 + i;
      uint4v h0, h1, h2, h3, h4, h5, h6, h7;
      if (v == 0) {
        const unsigned char* ap =
            hbuf + (size_t)((ri - 1) & 3) * SLOT_BYTES + vh;
        POLL8T(h0, h1, h2, h3, h4, h5, h6, h7, ap, (unsigned)ri);
        hsh[0][lane] = h0; hsh[1][lane] = h1; hsh[2][lane] = h2;
        hsh[3][lane] = h3; hsh[4][lane] = h4; hsh[5][lane] = h5;
        hsh[6][lane] = h6; hsh[7][lane] = h7;
      }
      __syncthreads();
      if (v < 3) {
        if (v != 0) {
          h0 = hsh[0][lane]; h1 = hsh[1][lane]; h2 = hsh[2][lane];
          h3 = hsh[3][lane]; h4 = hsh[4][lane]; h5 = hsh[5][lane];
          h6 = hsh[6][lane]; h7 = hsh[7][lane];
        }
        float4v a = {0.f, 0.f, 0.f, 0.f};
        MFMA_K8(a, Wf[2 + i], h0, h1, h2, h3, h4, h5, h6, h7);
        *(float4v*)&tiles[v][(lane & 15) * 20 + (lane >> 4) * 4] = a;
      }
      __syncthreads();
      float rr = sigf(tiles[0][ci]);
      float zz = sigf(tiles[1][ci]);
      float nn = tanh_fast(rr * tiles[2][ci]);
      hreg = (1.0f - zz) * nn + zz * hreg;
      if (i == NLAYERS - 1) {
        const bool act = (t < mylen);
        float hv = act ? hreg : hprev;   // freeze h past sequence end
        float ov = act ? hreg : 0.0f;    // out = m ? hn : 0
        hreg = hv;
        hprev = hv;
        out[((size_t)t * BATCH + c * 16 + row) * HID + w * 16 + col] = ov;
      }
      {
        float hp = __shfl_xor(hreg, 1);
        if (!(tid & 1)) {
          unsigned char* pp = hbuf + (size_t)(ri & 3) * SLOT_BYTES + pub_off;
          PUBLISH(pp, pack_bf16x2(hreg, hp), (unsigned)(ri + 1));
        }
      }
    }
  }
}

extern "C" void kernel_launch(void* const* d_in, const int* in_sizes, int n_in,
                              void* d_out, int out_size, void* d_ws, size_t ws_size,
                              hipStream_t stream) {
  (void)in_sizes; (void)n_in; (void)out_size; (void)ws_size;
  const float* x        = (const float*)d_in[0];
  const int* lengths    = (const int*)d_in[1];
  const float* Wr       = (const float*)d_in[2];
  const float* Wz       = (const float*)d_in[3];
  const float* Wl       = (const float*)d_in[4];
  const float* Wt       = (const float*)d_in[5];
  const float* Cx       = (const float*)d_in[6];
  const float* Ch       = (const float*)d_in[7];
  const float* Tr       = (const float*)d_in[8];
  const float* Tz       = (const float*)d_in[9];
  const float* Tn       = (const float*)d_in[10];

  unsigned char* hbuf = (unsigned char*)d_ws;

  // Ring init: all slots zero. tag 0 == "round -1 published"; slot 3 data
  // (zeros) is exactly h0. Must re-run every launch (ws is re-poisoned).
  hipMemsetAsync(hbuf, 0x00, HBUF_BYTES, stream);

  rnn_main<<<dim3(128), dim3(256), 0, stream>>>(
      x, lengths, Wr, Wz, Wl, Wt, Cx, Ch, Tr, Tz, Tn,
      hbuf, (float*)d_out);
}

// Round 5
// 7571.278 us; speedup vs baseline: 1.5079x; 1.3382x over previous
//
#include <hip/hip_runtime.h>
#include <hip/hip_bf16.h>
#include <string.h>

// Problem constants
#define T_STEPS 512
#define BATCH   128
#define DIM     256
#define HID     256
#define NLAYERS 4

typedef unsigned int  uint4v  __attribute__((ext_vector_type(4)));
typedef unsigned int  uint2v  __attribute__((ext_vector_type(2)));
typedef short         short8  __attribute__((ext_vector_type(8)));
typedef float         float4v __attribute__((ext_vector_type(4)));

// ws layout (TOTAL 512KB):
//   [0, 512KB) : h exchange ring, 4 slots x (8 clusters x 16 rows x 128 pairs
//                x 8B). pair = [bf16x2 packed h | 32-bit round tag]
//                (tag-in-data sync). R0-proven mechanism, unchanged.
#define SLOT_BYTES  (128 * 1024)
#define NSLOTS      4
#define HBUF_BYTES  (NSLOTS * SLOT_BYTES)

__device__ __forceinline__ short8 as_s8(uint4v u) {
  union { uint4v u; short8 s; } x; x.u = u; return x.s;
}
__device__ __forceinline__ float sigf(float x) {
  return 1.0f / (1.0f + __expf(-x));
}
__device__ __forceinline__ float tanh_fast(float x) {
  x = fminf(fmaxf(x, -15.0f), 15.0f);
  float e = __expf(2.0f * x);
  return (e - 1.0f) / (e + 1.0f);
}
// round-to-nearest-even f32 -> bf16 (inputs always finite here)
__device__ __forceinline__ unsigned short f2bf(float a) {
  unsigned ua = __builtin_bit_cast(unsigned, a);
  return (unsigned short)((ua + 0x7FFFu + ((ua >> 16) & 1u)) >> 16);
}
__device__ __forceinline__ unsigned pack_bf16x2(float a, float b) {
  return (unsigned)f2bf(a) | ((unsigned)f2bf(b) << 16);
}
__device__ __forceinline__ uint4v extract_frag(uint4v a, uint4v b) {
  uint4v f; f.x = a.x; f.y = a.z; f.z = b.x; f.w = b.z; return f;
}
__device__ __forceinline__ unsigned tagbad(uint4v a, uint4v b, unsigned tag) {
  return (a.y ^ tag) | (a.w ^ tag) | (b.y ^ tag) | (b.w ^ tag);
}

// 16 device-scope (sc0 sc1) 16B loads covering this lane's 8 A-fragments
// worth of [data|tag] pairs; single waitcnt INSIDE the asm — this is what
// makes the output registers safe to consume/reallocate after the macro
// (R4 lesson: counted-vmcnt exits leave in-flight writes that clobber
// compiler-reallocated VGPRs).
#define GLD16(A0,B0,A1,B1,A2,B2,A3,B3,A4,B4,A5,B5,A6,B6,A7,B7, ADDR)       \
  asm volatile(                                                             \
      "global_load_dwordx4 %0, %16, off offset:0 sc0 sc1\n\t"               \
      "global_load_dwordx4 %1, %16, off offset:16 sc0 sc1\n\t"              \
      "global_load_dwordx4 %2, %16, off offset:128 sc0 sc1\n\t"             \
      "global_load_dwordx4 %3, %16, off offset:144 sc0 sc1\n\t"             \
      "global_load_dwordx4 %4, %16, off offset:256 sc0 sc1\n\t"             \
      "global_load_dwordx4 %5, %16, off offset:272 sc0 sc1\n\t"             \
      "global_load_dwordx4 %6, %16, off offset:384 sc0 sc1\n\t"             \
      "global_load_dwordx4 %7, %16, off offset:400 sc0 sc1\n\t"             \
      "global_load_dwordx4 %8, %16, off offset:512 sc0 sc1\n\t"             \
      "global_load_dwordx4 %9, %16, off offset:528 sc0 sc1\n\t"             \
      "global_load_dwordx4 %10, %16, off offset:640 sc0 sc1\n\t"            \
      "global_load_dwordx4 %11, %16, off offset:656 sc0 sc1\n\t"            \
      "global_load_dwordx4 %12, %16, off offset:768 sc0 sc1\n\t"            \
      "global_load_dwordx4 %13, %16, off offset:784 sc0 sc1\n\t"            \
      "global_load_dwordx4 %14, %16, off offset:896 sc0 sc1\n\t"            \
      "global_load_dwordx4 %15, %16, off offset:912 sc0 sc1\n\t"            \
      "s_waitcnt vmcnt(0)"                                                  \
      : "=&v"(A0), "=&v"(B0), "=&v"(A1), "=&v"(B1),                         \
        "=&v"(A2), "=&v"(B2), "=&v"(A3), "=&v"(B3),                         \
        "=&v"(A4), "=&v"(B4), "=&v"(A5), "=&v"(B5),                         \
        "=&v"(A6), "=&v"(B6), "=&v"(A7), "=&v"(B7)                          \
      : "v"(ADDR)                                                           \
      : "memory")

// Poll until every consumed pair carries tag==TAG, then unpack 8 A-frags.
// Hot spin for 16 iters, then s_sleep(1) backoff. Stale reads only show OLD
// tags (monotonic) — never false-positive.
#define POLL8T(F0,F1,F2,F3,F4,F5,F6,F7, ADDR, TAG)                          \
  {                                                                         \
    uint4v _a0,_b0,_a1,_b1,_a2,_b2,_a3,_b3,_a4,_b4,_a5,_b5,_a6,_b6,_a7,_b7; \
    for (int _it = 0;; ++_it) {                                             \
      GLD16(_a0,_b0,_a1,_b1,_a2,_b2,_a3,_b3,_a4,_b4,_a5,_b5,_a6,_b6,_a7,_b7,\
            ADDR);                                                          \
      unsigned _bad = tagbad(_a0,_b0,TAG) | tagbad(_a1,_b1,TAG) |           \
                      tagbad(_a2,_b2,TAG) | tagbad(_a3,_b3,TAG) |           \
                      tagbad(_a4,_b4,TAG) | tagbad(_a5,_b5,TAG) |           \
                      tagbad(_a6,_b6,TAG) | tagbad(_a7,_b7,TAG);            \
      if (__all((int)(_bad == 0u)) || _it > (1 << 16)) break;               \
      if (_it >= 16) __builtin_amdgcn_s_sleep(1);                           \
    }                                                                       \
    F0 = extract_frag(_a0,_b0); F1 = extract_frag(_a1,_b1);                 \
    F2 = extract_frag(_a2,_b2); F3 = extract_frag(_a3,_b3);                 \
    F4 = extract_frag(_a4,_b4); F5 = extract_frag(_a5,_b5);                 \
    F6 = extract_frag(_a6,_b6); F7 = extract_frag(_a7,_b7);                 \
  }

// Publish: proven R0 form (sc0 sc1; R3 showed nt regresses).
#define PUBLISH(ADDR, PACKED, TAG)                                          \
  {                                                                         \
    uint2v _pv; _pv.x = (PACKED); _pv.y = (TAG);                            \
    asm volatile("global_store_dwordx2 %0, %1, off sc0 sc1"                 \
                 :: "v"(ADDR), "v"(_pv) : "memory");                        \
  }

// Publisher-side drain (R5 experiment): force the publish store out of any
// CU-side write buffering immediately. Only waves v!=0 run it — they are
// barrier-waiting anyway (fully hidden); v0's store already drains inside
// its first poll iteration's vmcnt(0).
#define DRAIN_STORES                                                        \
  { asm volatile("s_waitcnt vmcnt(0)" ::: "memory"); }

// h-part MFMAs split across TWO accumulators (4-deep chains instead of 8).
#define MFMA_K8_2(AX, AY, BARR, H0,H1,H2,H3,H4,H5,H6,H7)                             \
  AX = __builtin_amdgcn_mfma_f32_16x16x32_bf16(as_s8(H0), BARR[0], AX, 0, 0, 0);     \
  AY = __builtin_amdgcn_mfma_f32_16x16x32_bf16(as_s8(H1), BARR[1], AY, 0, 0, 0);     \
  AX = __builtin_amdgcn_mfma_f32_16x16x32_bf16(as_s8(H2), BARR[2], AX, 0, 0, 0);     \
  AY = __builtin_amdgcn_mfma_f32_16x16x32_bf16(as_s8(H3), BARR[3], AY, 0, 0, 0);     \
  AX = __builtin_amdgcn_mfma_f32_16x16x32_bf16(as_s8(H4), BARR[4], AX, 0, 0, 0);     \
  AY = __builtin_amdgcn_mfma_f32_16x16x32_bf16(as_s8(H5), BARR[5], AY, 0, 0, 0);     \
  AX = __builtin_amdgcn_mfma_f32_16x16x32_bf16(as_s8(H6), BARR[6], AX, 0, 0, 0);     \
  AY = __builtin_amdgcn_mfma_f32_16x16x32_bf16(as_s8(H7), BARR[7], AY, 0, 0, 0);

// ---------------------------------------------------------------------------
// Main recurrent kernel. 8 clusters (batch slices of 16) x 16 wgs (each owns
// 16 hidden columns) x 256 threads (4 waves). ALL tensors are FLOAT32; bf16
// exists only as MFMA operands. Weight B-frags persist in VGPRs.
// Structure = R0-proven (4-slot tag-in-data ring, v0-only single-set poll +
// LDS broadcast, publish-immediately-after-combine). R5 deltas (each audited
// race-free / register-safe):
//  * wave v1 prefetches next step's x into LDS during its idle window
//    (loads issued at transition i==0, packed+staged at i==1; all WAR pairs
//    separated by >=2 barriers); round A reads xf from LDS, removing an HBM
//    load from the serial path
//  * h-part MFMA chains split into 2 accumulators (4-deep, not 8)
//  * publisher store drain for waves v!=0 (hidden under barrier wait)
// ---------------------------------------------------------------------------
__launch_bounds__(256, 1)
__global__ void rnn_main(const float* __restrict__ x,
                         const int* __restrict__ lengths,
                         const float* __restrict__ Wr,
                         const float* __restrict__ Wz,
                         const float* __restrict__ Wl,
                         const float* __restrict__ Wt,
                         const float* __restrict__ Cx,
                         const float* __restrict__ Ch,
                         const float* __restrict__ Tr,
                         const float* __restrict__ Tz,
                         const float* __restrict__ Tn,
                         unsigned char* __restrict__ hbuf,
                         float* __restrict__ out) {
  const int tid  = threadIdx.x;
  const int lane = tid & 63;
  const int v    = tid >> 6;
  const int bid  = blockIdx.x;
  const int c    = bid & 7;    // cluster (batch slice)
  const int w    = bid >> 3;   // column-chunk owner within cluster

  __shared__ float  tiles[6][16 * 20];  // col-major, col stride 20
  __shared__ uint4v hsh[8][64];         // polled A-frag broadcast (8 KB)
  __shared__ uint4v xsh[8][64];         // prefetched packed x frags (8 KB)
  __shared__ int    len_sh[16];

  // ---- load + convert persistent weight B-fragments (one-time gather) ----
  // Fragment layout: lane l holds B[k = kt*32 + (l>>4)*8 + j][col0 + (l&15)].
  // Matrix ids: 0..2 = W{r,z,l}[256:512] (h-part), 3 = Ch, 4..6 = W{r,z,l}
  // [0:256] (x-part), 7 = Cx, 8 = Wt, 9..12 = Tr_i, 13..16 = Tz_i,
  // 17..20 = Tn_i.
  short8 Wf[6][8];
  {
    const int SCHED[4][6] = {{0, 4, 9, 10, 11, 12},
                             {1, 5, 13, 14, 15, 16},
                             {2, 6, 17, 18, 19, 20},
                             {3, 7, 8, 3, 3, 3}};
    const int colg = w * 16 + (lane & 15);
#pragma unroll
    for (int s = 0; s < 6; ++s) {
      const int m = SCHED[v][s];
      const float* base;
      int ro = 0;
      if      (m == 0)  { base = Wr; ro = 256; }
      else if (m == 1)  { base = Wz; ro = 256; }
      else if (m == 2)  { base = Wl; ro = 256; }
      else if (m == 3)  { base = Ch; }
      else if (m == 4)  { base = Wr; }
      else if (m == 5)  { base = Wz; }
      else if (m == 6)  { base = Wl; }
      else if (m == 7)  { base = Cx; }
      else if (m == 8)  { base = Wt; }
      else if (m <= 12) { base = Tr + (size_t)(m - 9)  * HID * HID; }
      else if (m <= 16) { base = Tz + (size_t)(m - 13) * HID * HID; }
      else              { base = Tn + (size_t)(m - 17) * HID * HID; }
#pragma unroll
      for (int kt = 0; kt < 8; ++kt) {
        const int k0 = ro + kt * 32 + (lane >> 4) * 8;
        short8 f;
#pragma unroll
        for (int j = 0; j < 8; ++j)
          f[j] = (short)f2bf(base[(size_t)(k0 + j) * HID + colg]);
        Wf[s][kt] = f;
      }
    }
  }

  if (tid < 16) len_sh[tid] = lengths[c * 16 + tid];

  const float* xbase =
      x + ((size_t)c * 16 + (lane & 15)) * DIM + (lane >> 4) * 8;

  // Prologue: v1 stages packed x for t=0 into xsh (blocking; once).
  if (v == 1) {
#pragma unroll
    for (int kt = 0; kt < 8; ++kt) {
      float4v xa = *(const float4v*)(xbase + kt * 32);
      float4v xb = *(const float4v*)(xbase + kt * 32 + 4);
      uint4v f;
      f.x = pack_bf16x2(xa.x, xa.y);
      f.y = pack_bf16x2(xa.z, xa.w);
      f.z = pack_bf16x2(xb.x, xb.y);
      f.w = pack_bf16x2(xb.z, xb.w);
      xsh[kt][lane] = f;
    }
  }
  __syncthreads();

  const int row = tid >> 4;
  const int col = tid & 15;
  const int mylen = len_sh[row];
  const int ci = col * 20 + row;

  float hreg = 0.0f, hprev = 0.0f;

  // lane byte offset into an h slot for A-frag [data|tag] pair loads:
  // pairs laid out [c*16+row][128 pairs]; lane reads row (lane&15),
  // quarter (lane>>4): base = row*1024 + (lane>>4)*32, frag kt at +kt*128.
  const unsigned vh = (unsigned)((c * 16 + (lane & 15)) * 1024 + (lane >> 4) * 32);
  // per-EVEN-thread publish offset: row=tid>>4, colpair=(tid&15)>>1
  const unsigned pub_off =
      (unsigned)(((c * 16 + (tid >> 4)) * 128 + w * 8 + ((tid & 15) >> 1)) * 8);

  for (int t = 0; t < T_STEPS; ++t) {
    const int r0 = t * 5;
    float4v xra[8], xrb[8];   // v1's raw next-step x (live i==0 -> i==1)
    // ======================= round A (cell gates) =======================
    {
      uint4v xf[8];
#pragma unroll
      for (int kt = 0; kt < 8; ++kt) xf[kt] = xsh[kt][lane];

      float4v a0 = {0.f, 0.f, 0.f, 0.f};
      float4v a1 = {0.f, 0.f, 0.f, 0.f};
      float4v a2 = {0.f, 0.f, 0.f, 0.f};
      // x-dependent MFMAs issue first: the MFMA pipe crunches them while
      // v0 polls / others wait at the barrier.
      if (v < 3) {
#pragma unroll
        for (int kt = 0; kt < 8; ++kt)
          a0 = __builtin_amdgcn_mfma_f32_16x16x32_bf16(as_s8(xf[kt]), Wf[1][kt], a0, 0, 0, 0);
      } else {
#pragma unroll
        for (int kt = 0; kt < 8; ++kt)
          a1 = __builtin_amdgcn_mfma_f32_16x16x32_bf16(as_s8(xf[kt]), Wf[1][kt], a1, 0, 0, 0);
#pragma unroll
        for (int kt = 0; kt < 8; ++kt)
          a2 = __builtin_amdgcn_mfma_f32_16x16x32_bf16(as_s8(xf[kt]), Wf[2][kt], a2, 0, 0, 0);
      }
      uint4v h0, h1, h2, h3, h4, h5, h6, h7;
      if (v == 0) {
        const unsigned char* ap =
            hbuf + (size_t)((r0 - 1) & 3) * SLOT_BYTES + vh;
        POLL8T(h0, h1, h2, h3, h4, h5, h6, h7, ap, (unsigned)r0);
        hsh[0][lane] = h0; hsh[1][lane] = h1; hsh[2][lane] = h2;
        hsh[3][lane] = h3; hsh[4][lane] = h4; hsh[5][lane] = h5;
        hsh[6][lane] = h6; hsh[7][lane] = h7;
      }
      __syncthreads();
      if (v != 0) {
        h0 = hsh[0][lane]; h1 = hsh[1][lane]; h2 = hsh[2][lane];
        h3 = hsh[3][lane]; h4 = hsh[4][lane]; h5 = hsh[5][lane];
        h6 = hsh[6][lane]; h7 = hsh[7][lane];
      }
      {
        float4v ahx = {0.f, 0.f, 0.f, 0.f};
        float4v ahy = {0.f, 0.f, 0.f, 0.f};
        MFMA_K8_2(ahx, ahy, Wf[0], h0, h1, h2, h3, h4, h5, h6, h7);
        a0 = a0 + ahx + ahy;
      }
      {
        float* tp = &tiles[(v < 3) ? v : 3][(lane & 15) * 20 + (lane >> 4) * 4];
        *(float4v*)tp = a0;
        if (v == 3) {
          *(float4v*)&tiles[4][(lane & 15) * 20 + (lane >> 4) * 4] = a1;
          *(float4v*)&tiles[5][(lane & 15) * 20 + (lane >> 4) * 4] = a2;
        }
      }
      __syncthreads();
      float rp  = tiles[0][ci], zp = tiles[1][ci], lp = tiles[2][ci];
      float chv = tiles[3][ci], xcv = tiles[4][ci], xwv = tiles[5][ci];
      float r  = sigf(rp), z = sigf(zp), lg = sigf(lp);
      float n  = tanh_fast(xcv + r * chv) + lg * xwv;
      hreg = (1.0f - z) * hreg + z * n;
      // publish NOW: pair even/odd columns in-register, even threads store.
      {
        float hp = __shfl_xor(hreg, 1);
        if (!(tid & 1)) {
          unsigned char* pp = hbuf + (size_t)(r0 & 3) * SLOT_BYTES + pub_off;
          PUBLISH(pp, pack_bf16x2(hreg, hp), (unsigned)(r0 + 1));
        }
        if (v != 0) DRAIN_STORES;
      }
    }
    // ======================= transition layers =======================
#pragma unroll
    for (int i = 0; i < NLAYERS; ++i) {
      const int ri = r0 + 1 + i;
      // v1 x-prefetch pipeline (hidden in v1's idle-at-barrier window):
      //   i==0: issue next step's 16 raw loads
      //   i==1: pack + stage into xsh (loads long retired by the i==0 drain)
      if (v == 1 && t + 1 < T_STEPS) {
        if (i == 0) {
          const float* xq = xbase + (size_t)(t + 1) * BATCH * DIM;
#pragma unroll
          for (int kt = 0; kt < 8; ++kt) {
            xra[kt] = *(const float4v*)(xq + kt * 32);
            xrb[kt] = *(const float4v*)(xq + kt * 32 + 4);
          }
        }
        if (i == 1) {
#pragma unroll
          for (int kt = 0; kt < 8; ++kt) {
            uint4v f;
            f.x = pack_bf16x2(xra[kt].x, xra[kt].y);
            f.y = pack_bf16x2(xra[kt].z, xra[kt].w);
            f.z = pack_bf16x2(xrb[kt].x, xrb[kt].y);
            f.w = pack_bf16x2(xrb[kt].z, xrb[kt].w);
            xsh[kt][lane] = f;
          }
        }
      }
      uint4v h0, h1, h2, h3, h4, h5, h6, h7;
      if (v == 0) {
        const unsigned char* ap =
            hbuf + (size_t)((ri - 1) & 3) * SLOT_BYTES + vh;
        POLL8T(h0, h1, h2, h3, h4, h5, h6, h7, ap, (unsigned)ri);
        hsh[0][lane] = h0; hsh[1][lane] = h1; hsh[2][lane] = h2;
        hsh[3][lane] = h3; hsh[4][lane] = h4; hsh[5][lane] = h5;
        hsh[6][lane] = h6; hsh[7][lane] = h7;
      }
      __syncthreads();
      if (v < 3) {
        if (v != 0) {
          h0 = hsh[0][lane]; h1 = hsh[1][lane]; h2 = hsh[2][lane];
          h3 = hsh[3][lane]; h4 = hsh[4][lane]; h5 = hsh[5][lane];
          h6 = hsh[6][lane]; h7 = hsh[7][lane];
        }
        float4v ahx = {0.f, 0.f, 0.f, 0.f};
        float4v ahy = {0.f, 0.f, 0.f, 0.f};
        MFMA_K8_2(ahx, ahy, Wf[2 + i], h0, h1, h2, h3, h4, h5, h6, h7);
        ahx = ahx + ahy;
        *(float4v*)&tiles[v][(lane & 15) * 20 + (lane >> 4) * 4] = ahx;
      }
      __syncthreads();
      float rr = sigf(tiles[0][ci]);
      float zz = sigf(tiles[1][ci]);
      float nn = tanh_fast(rr * tiles[2][ci]);
      hreg = (1.0f - zz) * nn + zz * hreg;
      if (i == NLAYERS - 1) {
        const bool act = (t < mylen);
        float hv = act ? hreg : hprev;   // freeze h past sequence end
        float ov = act ? hreg : 0.0f;    // out = m ? hn : 0
        hreg = hv;
        hprev = hv;
        out[((size_t)t * BATCH + c * 16 + row) * HID + w * 16 + col] = ov;
      }
      {
        float hp = __shfl_xor(hreg, 1);
        if (!(tid & 1)) {
          unsigned char* pp = hbuf + (size_t)(ri & 3) * SLOT_BYTES + pub_off;
          PUBLISH(pp, pack_bf16x2(hreg, hp), (unsigned)(ri + 1));
        }
        if (v != 0) DRAIN_STORES;
      }
    }
  }
}

extern "C" void kernel_launch(void* const* d_in, const int* in_sizes, int n_in,
                              void* d_out, int out_size, void* d_ws, size_t ws_size,
                              hipStream_t stream) {
  (void)in_sizes; (void)n_in; (void)out_size; (void)ws_size;
  const float* x        = (const float*)d_in[0];
  const int* lengths    = (const int*)d_in[1];
  const float* Wr       = (const float*)d_in[2];
  const float* Wz       = (const float*)d_in[3];
  const float* Wl       = (const float*)d_in[4];
  const float* Wt       = (const float*)d_in[5];
  const float* Cx       = (const float*)d_in[6];
  const float* Ch       = (const float*)d_in[7];
  const float* Tr       = (const float*)d_in[8];
  const float* Tz       = (const float*)d_in[9];
  const float* Tn       = (const float*)d_in[10];

  unsigned char* hbuf = (unsigned char*)d_ws;

  // Ring init: all slots zero. tag 0 == "round -1 published"; slot 3 data
  // (zeros) is exactly h0. Must re-run every launch (ws is re-poisoned).
  hipMemsetAsync(hbuf, 0x00, HBUF_BYTES, stream);

  rnn_main<<<dim3(128), dim3(256), 0, stream>>>(
      x, lengths, Wr, Wz, Wl, Wt, Cx, Ch, Tr, Tz, Tn,
      hbuf, (float*)d_out);
}